// Round 18
// baseline (74.718 us; speedup 1.0000x reference)
//
#include <hip/hip_runtime.h>
#include <stdint.h>
#include <stddef.h>

#define E_DIM 1024

typedef __bf16 v8bf __attribute__((ext_vector_type(8)));
typedef float v4f __attribute__((ext_vector_type(4)));

__device__ __forceinline__ unsigned short f2bf(float x) {
  unsigned int u = __builtin_bit_cast(unsigned int, x);
  u += 0x7fffu + ((u >> 16) & 1u);
  return (unsigned short)(u >> 16);
}

// XOR swizzle for LDS rows >= 128B (involution; both-sides-or-neither).
template <int RB>
__device__ __forceinline__ int swz(int r, int c) {
  if constexpr (RB >= 128) return c ^ ((r & 7) << 4);
  else return c;
}

// constexpr-dispatched s_waitcnt vmcnt(N)
template <int N>
__device__ __forceinline__ void waitcnt_vm() {
  static_assert(N == 0 || N == 4 || N == 8 || N == 12 || N == 16, "add literal");
  if constexpr (N == 0)  asm volatile("s_waitcnt vmcnt(0)" ::: "memory");
  if constexpr (N == 4)  asm volatile("s_waitcnt vmcnt(4)" ::: "memory");
  if constexpr (N == 8)  asm volatile("s_waitcnt vmcnt(8)" ::: "memory");
  if constexpr (N == 12) asm volatile("s_waitcnt vmcnt(12)" ::: "memory");
  if constexpr (N == 16) asm volatile("s_waitcnt vmcnt(16)" ::: "memory");
}

// bf16 global tile (ROWS x BK) -> LDS via global_load_lds, source pre-swizzled.
template <int ROWS, int BK>
__device__ __forceinline__ void stageg(const unsigned short* __restrict__ G, int g0,
                                       int ldg, int k0, char* L, int wid, int lane) {
  constexpr int RB = BK * 2;
  constexpr int ITERS = (ROWS * RB) / 4096;
#pragma unroll
  for (int it = 0; it < ITERS; ++it) {
    int lbase = it * 4096 + wid * 1024;   // wave-uniform LDS byte base
    int lin = lbase + lane * 16;
    int r = lin / RB, cb = lin % RB;
    int gcb = swz<RB>(r, cb);
    const char* g = (const char*)G + ((size_t)(g0 + r) * ldg + k0) * 2 + gcb;
    __builtin_amdgcn_global_load_lds((const __attribute__((address_space(1))) void*)g,
                                     (__attribute__((address_space(3))) void*)(L + lbase),
                                     16, 0, 0);
  }
}

template <int RB>
__device__ __forceinline__ v8bf frag_bf16(const char* L, int r, int kelem) {
  int o = swz<RB>(r, kelem * 2);
  return *(const v8bf*)(L + r * RB + o);
}

// one K-tile of MFMA work from bf16 LDS buffers
template <int BM, int BN, int BK, int FM, int FN>
__device__ __forceinline__ void compute_tile(const char* Al, const char* Bl,
                                             v4f (&acc)[FM][FN],
                                             int wr, int wc, int lr, int kg) {
  constexpr int RBA = BK * 2, RBB = BK * 2;
  constexpr int TMW = BM / 2, TNW = BN / 2;
#pragma unroll
  for (int kk = 0; kk < BK / 32; ++kk) {
    const int ke = kk * 32 + kg * 8;
    v8bf a[FM], b[FN];
#pragma unroll
    for (int mi = 0; mi < FM; ++mi)
      a[mi] = frag_bf16<RBA>(Al, wr * TMW + mi * 16 + lr, ke);
#pragma unroll
    for (int ni = 0; ni < FN; ++ni)
      b[ni] = frag_bf16<RBB>(Bl, wc * TNW + ni * 16 + lr, ke);
#pragma unroll
    for (int mi = 0; mi < FM; ++mi)
#pragma unroll
      for (int ni = 0; ni < FN; ++ni)
        acc[mi][ni] = __builtin_amdgcn_mfma_f32_16x16x32_bf16(a[mi], b[ni], acc[mi][ni], 0, 0, 0);
  }
}

// cvt 4096 fp32 -> bf16 per block; i0 = (base + blkrel) * 1024 + tid
__device__ __forceinline__ void cvt4(const float4* __restrict__ src,
                                     ushort4* __restrict__ dst, int i0) {
#pragma unroll
  for (int j = 0; j < 4; ++j) {
    int i = i0 + j * 256;
    float4 f = src[i];
    ushort4 u;
    u.x = f2bf(f.x); u.y = f2bf(f.y); u.z = f2bf(f.z); u.w = f2bf(f.w);
    dst[i] = u;
  }
}

// matvec: 4 rows/block, y = W@x + b over 1024 cols (W fp32)
__device__ __forceinline__ void mv4(const float* __restrict__ W, const float* __restrict__ x,
                                    const float* __restrict__ b, float* __restrict__ y,
                                    int blkrel, int tid) {
  int r = blkrel * 4 + (tid >> 6);
  int lane = tid & 63;
  float s = 0.f;
  for (int c = lane; c < 1024; c += 64) s += W[(size_t)r * 1024 + c] * x[c];
#pragma unroll
  for (int off = 32; off; off >>= 1) s += __shfl_down(s, off);
  if (lane == 0) y[r] = s + b[r];
}

// K4f A-path: load 128x64 fp32 tile into 8 float4 regs (coalesced 256B rows)
__device__ __forceinline__ void lda_k4(const float* __restrict__ A, int bm0, int k0,
                                       int tid, float4 (&r)[8]) {
#pragma unroll
  for (int p = 0; p < 8; ++p) {
    int i4 = p * 256 + tid;
    int row = i4 >> 4, c4 = i4 & 15;
    r[p] = *(const float4*)(A + (size_t)(bm0 + row) * 512 + k0 + c4 * 4);
  }
}

// K4f A-path: cvt + ds_write into RB=128 swizzled bf16 LDS tile (8B chunks;
// 8B offset lives below the XORed bits 4-6 -> same involution as frag reads)
__device__ __forceinline__ void wra_k4(const float4 (&r)[8], char* L, int tid) {
#pragma unroll
  for (int p = 0; p < 8; ++p) {
    int i4 = p * 256 + tid;
    int row = i4 >> 4, c4 = i4 & 15;
    ushort4 u;
    u.x = f2bf(r[p].x); u.y = f2bf(r[p].y); u.z = f2bf(r[p].z); u.w = f2bf(r[p].w);
    *(ushort4*)(L + row * 128 + swz<128>(row, c4 * 8)) = u;
  }
}

// ---- prep1 (weights only): transpose+cvt Wv [0,512) || matvec b1 [512,768)
//                            || cvt Wiv [768,1024)
__global__ __launch_bounds__(256) void prep1(const float* __restrict__ Wv,
                                             unsigned short* __restrict__ WvT,
                                             const float* __restrict__ Wiv,
                                             const float* __restrict__ bv,
                                             const float* __restrict__ biv,
                                             float* __restrict__ b1,
                                             unsigned short* __restrict__ Wivb) {
  int bid = blockIdx.x;
  int tid = threadIdx.x;
  if (bid < 512) {
    __shared__ float tile[32][33];
    const int R = 1024, C = 512;
    int nbx = C >> 5;
    int bx = bid % nbx, by = bid / nbx;
    int tx = tid & 31, ty = tid >> 5;
#pragma unroll
    for (int i = 0; i < 32; i += 8)
      tile[ty + i][tx] = Wv[(size_t)(by * 32 + ty + i) * C + bx * 32 + tx];
    __syncthreads();
#pragma unroll
    for (int i = 0; i < 32; i += 8)
      WvT[(size_t)(bx * 32 + ty + i) * R + by * 32 + tx] = f2bf(tile[tx][ty + i]);
  } else if (bid < 768) {
    mv4(Wiv, bv, biv, b1, bid - 512, tid);
  } else {
    cvt4((const float4*)Wiv, (ushort4*)Wivb, (bid - 768) * 1024 + tid);
  }
}

// ---- generic bt-GEMM (K2/K3), depth-4 buffers / 3-in-flight, 1 barrier/phase.
// NT = K/BK multiple of 4 >= 8.
// Tail blocks (>= ngemm): [0,nmv) matvec; [nmv,nmv+ncv1) cvt1; rest cvt2.
template <int BM, int BN, int BK, int FM, int FN, int OUTBF, int XCDSWZ>
__global__ __launch_bounds__(256) void gemm_cv(const unsigned short* __restrict__ A,
                                               const unsigned short* __restrict__ B,
                                               const float* __restrict__ bias,
                                               float* __restrict__ Cf,
                                               unsigned short* __restrict__ Cb,
                                               int M, int N, int K,
                                               const float* __restrict__ mvW,
                                               const float* __restrict__ mvx,
                                               const float* __restrict__ mvb,
                                               float* __restrict__ mvy, int nmv,
                                               const float* __restrict__ csrc1,
                                               unsigned short* __restrict__ cdst1,
                                               int cbase1, int ncv1,
                                               const float* __restrict__ csrc2,
                                               unsigned short* __restrict__ cdst2,
                                               int cbase2) {
  static_assert((BM + BN) * BK * 2 / 1024 / 4 == 4, "vmcnt literals assume 4 loads/tile/wave");
  __shared__ __align__(16) char Al0[BM * BK * 2];
  __shared__ __align__(16) char Al1[BM * BK * 2];
  __shared__ __align__(16) char Al2[BM * BK * 2];
  __shared__ __align__(16) char Al3[BM * BK * 2];
  __shared__ __align__(16) char Bl0[BN * BK * 2];
  __shared__ __align__(16) char Bl1[BN * BK * 2];
  __shared__ __align__(16) char Bl2[BN * BK * 2];
  __shared__ __align__(16) char Bl3[BN * BK * 2];
  const int nbn = N / BN;
  const int ngemm = nbn * (M / BM);
  int bid = blockIdx.x;
  const int tid = threadIdx.x;

  if (bid >= ngemm) {  // tail work
    int rel = bid - ngemm;
    if (rel < nmv) {
      mv4(mvW, mvx, mvb, mvy, rel, tid);
    } else if (rel < nmv + ncv1) {
      cvt4((const float4*)csrc1, (ushort4*)cdst1, (cbase1 + rel - nmv) * 1024 + tid);
    } else {
      cvt4((const float4*)csrc2, (ushort4*)cdst2, (cbase2 + rel - nmv - ncv1) * 1024 + tid);
    }
    return;
  }

  int bm_i, bn_i;
  if (XCDSWZ) {
    int x = bid & 7, j = bid >> 3;
    bm_i = x + ((j >> 3) << 3);
    bn_i = j & 7;
  } else {
    bm_i = bid / nbn;
    bn_i = bid % nbn;
  }
  const int bm0 = bm_i * BM, bn0 = bn_i * BN;

  constexpr int TMW = BM / 2, TNW = BN / 2;
  const int lane = tid & 63;
  const int wid = tid >> 6;
  const int wr = wid >> 1, wc = wid & 1;
  const int lr = lane & 15;
  const int kg = lane >> 4;

  v4f acc[FM][FN];
#pragma unroll
  for (int i = 0; i < FM; ++i)
#pragma unroll
    for (int j = 0; j < FN; ++j) acc[i][j] = 0.f;

  const int NT = K / BK;  // multiple of 4, >= 8

  stageg<BM, BK>(A, bm0, K, 0 * BK, Al0, wid, lane);
  stageg<BN, BK>(B, bn0, K, 0 * BK, Bl0, wid, lane);
  stageg<BM, BK>(A, bm0, K, 1 * BK, Al1, wid, lane);
  stageg<BN, BK>(B, bn0, K, 1 * BK, Bl1, wid, lane);
  stageg<BM, BK>(A, bm0, K, 2 * BK, Al2, wid, lane);
  stageg<BN, BK>(B, bn0, K, 2 * BK, Bl2, wid, lane);

#define GEMM_PHASE(CA, CB, SA, SB, TNXT, W)                              \
  waitcnt_vm<W>();                                                       \
  __builtin_amdgcn_s_barrier();                                          \
  __builtin_amdgcn_sched_barrier(0);                                     \
  if ((TNXT) < NT) {                                                     \
    stageg<BM, BK>(A, bm0, K, (TNXT)*BK, SA, wid, lane);                 \
    stageg<BN, BK>(B, bn0, K, (TNXT)*BK, SB, wid, lane);                 \
  }                                                                      \
  __builtin_amdgcn_s_setprio(1);                                         \
  compute_tile<BM, BN, BK, FM, FN>(CA, CB, acc, wr, wc, lr, kg);         \
  __builtin_amdgcn_s_setprio(0);                                         \
  __builtin_amdgcn_sched_barrier(0);

  for (int t = 0; t + 8 <= NT; t += 4) {
    GEMM_PHASE(Al0, Bl0, Al3, Bl3, t + 3, 8)
    GEMM_PHASE(Al1, Bl1, Al0, Bl0, t + 4, 8)
    GEMM_PHASE(Al2, Bl2, Al1, Bl1, t + 5, 8)
    GEMM_PHASE(Al3, Bl3, Al2, Bl2, t + 6, 8)
  }
  GEMM_PHASE(Al0, Bl0, Al3, Bl3, NT - 1, 8)
  GEMM_PHASE(Al1, Bl1, Al0, Bl0, NT, 8)
  GEMM_PHASE(Al2, Bl2, Al1, Bl1, NT, 4)
  GEMM_PHASE(Al3, Bl3, Al2, Bl2, NT, 0)
#undef GEMM_PHASE

#pragma unroll
  for (int ni = 0; ni < FN; ++ni) {
    int col = bn0 + wc * TNW + ni * 16 + lr;
    float bz = bias ? bias[col] : 0.f;
#pragma unroll
    for (int mi = 0; mi < FM; ++mi) {
      int row0 = bm0 + wr * TMW + mi * 16 + kg * 4;
#pragma unroll
      for (int r = 0; r < 4; ++r) {
        float v = acc[mi][ni][r] + bz;
        if (OUTBF) Cb[(size_t)(row0 + r) * N + col] = f2bf(v);
        else       Cf[(size_t)(row0 + r) * N + col] = v;
      }
    }
  }
}

// ---- K4f: 128x128 tile, BK=64, RB=128 swizzle, depth-2, NT=8 static.
// A = vit fp32 reg-staged (8 float4/thread, cvt->ds_write one phase after
// issue); B = Wcb bf16 via global_load_lds. Counted vmcnt: per phase bottom,
// issue 12 vmem for tile t+2, vmcnt(12) retires tile t+1's 12, cvt-write
// A(t+1) into the buffer consumed next phase (race-free: the buffer's prior
// tile was consumed before this phase's second barrier).
__global__ __launch_bounds__(256) void gemm_k4f(const float* __restrict__ A,
                                                const unsigned short* __restrict__ B,
                                                const float* __restrict__ bias,
                                                float* __restrict__ C) {
  constexpr int N = 1024;
  __shared__ __align__(16) char Al0[128 * 128];
  __shared__ __align__(16) char Al1[128 * 128];
  __shared__ __align__(16) char Bl0[128 * 128];
  __shared__ __align__(16) char Bl1[128 * 128];
  const int tid = threadIdx.x;
  const int lane = tid & 63, wid = tid >> 6;
  const int wr = wid >> 1, wc = wid & 1;
  const int lr = lane & 15, kg = lane >> 4;

  int bid = blockIdx.x;           // 1024 blocks, nbn = 8
  int x = bid & 7, j = bid >> 3;  // XCD row-band swizzle (proven)
  const int bm0 = (x + ((j >> 3) << 3)) * 128;
  const int bn0 = (j & 7) * 128;

  v4f acc[4][4];
#pragma unroll
  for (int i = 0; i < 4; ++i)
#pragma unroll
    for (int jj = 0; jj < 4; ++jj) acc[i][jj] = 0.f;

  float4 ra[8], rb[8];  // two named reg sets (tiles of matching parity)

  // prologue: issue a(0)[8], B(0)[4], a(1)[8], B(1)[4] -> 24 outstanding
  lda_k4(A, bm0, 0, tid, ra);
  stageg<128, 64>(B, bn0, 512, 0, Bl0, wid, lane);
  lda_k4(A, bm0, 64, tid, rb);
  stageg<128, 64>(B, bn0, 512, 64, Bl1, wid, lane);
  waitcnt_vm<16>();               // a(0) done
  wra_k4(ra, Al0, tid);
  waitcnt_vm<12>();               // B(0) done (a(1)+B(1) remain)

// phase t: consume (CA,CB); bottom: issue tile TN2 (regs RS + B->CB),
// vmcnt(W) retires tile t+1's loads, cvt-write RW -> AW (tile t+1).
#define K4FP(CA, CB, RS, RW, AW, TN2, W)                                 \
  asm volatile("s_waitcnt lgkmcnt(0)" ::: "memory");                     \
  __builtin_amdgcn_s_barrier();                                          \
  __builtin_amdgcn_sched_barrier(0);                                     \
  __builtin_amdgcn_s_setprio(1);                                         \
  compute_tile<128, 128, 64, 4, 4>(CA, CB, acc, wr, wc, lr, kg);         \
  __builtin_amdgcn_s_setprio(0);                                         \
  __builtin_amdgcn_sched_barrier(0);                                     \
  __builtin_amdgcn_s_barrier();                                          \
  if constexpr ((TN2) < 8) {                                             \
    lda_k4(A, bm0, (TN2)*64, tid, RS);                                   \
    stageg<128, 64>(B, bn0, 512, (TN2)*64, CB, wid, lane);               \
  }                                                                      \
  if constexpr ((TN2) <= 8) {                                            \
    waitcnt_vm<((TN2) < 8) ? 12 : 0>();                                  \
    wra_k4(RW, AW, tid);                                                 \
  }                                                                      \
  __builtin_amdgcn_sched_barrier(0);

  K4FP(Al0, Bl0, ra, rb, Al1, 2, 12)   // t=0: stage 2, write tile1
  K4FP(Al1, Bl1, rb, ra, Al0, 3, 12)   // t=1: stage 3, write tile2
  K4FP(Al0, Bl0, ra, rb, Al1, 4, 12)   // t=2
  K4FP(Al1, Bl1, rb, ra, Al0, 5, 12)   // t=3
  K4FP(Al0, Bl0, ra, rb, Al1, 6, 12)   // t=4
  K4FP(Al1, Bl1, rb, ra, Al0, 7, 12)   // t=5
  K4FP(Al0, Bl0, ra, rb, Al1, 8, 0)    // t=6: no issue, drain, write tile7
  // t=7: final compute, no bottom
  asm volatile("s_waitcnt lgkmcnt(0)" ::: "memory");
  __builtin_amdgcn_s_barrier();
  __builtin_amdgcn_s_setprio(1);
  compute_tile<128, 128, 64, 4, 4>(Al1, Bl1, acc, wr, wc, lr, kg);
  __builtin_amdgcn_s_setprio(0);
#undef K4FP

#pragma unroll
  for (int ni = 0; ni < 4; ++ni) {
    int col = bn0 + wc * 64 + ni * 16 + lr;
    float bz = bias[col];
#pragma unroll
    for (int mi = 0; mi < 4; ++mi) {
      int row0 = bm0 + wr * 64 + mi * 16 + kg * 4;
#pragma unroll
      for (int r = 0; r < 4; ++r)
        C[(size_t)(row0 + r) * N + col] = acc[mi][ni][r] + bz;
    }
  }
}

extern "C" void kernel_launch(void* const* d_in, const int* in_sizes, int n_in,
                              void* d_out, int out_size, void* d_ws, size_t ws_size,
                              hipStream_t stream) {
  // softmax over singleton axis == 1  =>  out = x @ (Wo·Wiv·Wv)^T + [Wo·(Wiv·bv+biv)+bo]
  const float* vit = (const float*)d_in[1];
  const float* Wv  = (const float*)d_in[6];
  const float* bv  = (const float*)d_in[7];
  const float* ipw = (const float*)d_in[8];
  const float* ipb = (const float*)d_in[9];
  const float* Wo  = (const float*)d_in[10];
  const float* bo  = (const float*)d_in[11];
  const float* Wiv = ipw + 2 * E_DIM * E_DIM;
  const float* biv = ipb + 2 * E_DIM;

  char* ws = (char*)d_ws;
  unsigned short* Wivb = (unsigned short*)(ws);              // 1024x1024 bf16, 2 MB
  unsigned short* Wob  = (unsigned short*)(ws + (2 << 20));  // 1024x1024 bf16, 2 MB
  unsigned short* WvTb = (unsigned short*)(ws + (4 << 20));  // 512x1024 bf16, 1 MB
  unsigned short* Ttb  = (unsigned short*)(ws + (5 << 20));  // 512x1024 bf16 (T^T)
  unsigned short* Wcb  = (unsigned short*)(ws + (6 << 20));  // 1024x512 bf16
  float* b1 = (float*)(ws + (7 << 20));
  float* bc = (float*)(ws + (7 << 20) + 4096);

  // K1 (weights only): transpose Wv -> WvT || matvec b1 || cvt Wiv
  prep1<<<1024, 256, 0, stream>>>(Wv, WvTb, Wiv, bv, biv, b1, Wivb);

  // K2: T^T = WvT @ Wiv^T (128) || bc matvec (256) || cvt Wo (256)
  gemm_cv<64, 64, 64, 2, 2, 1, 0><<<128 + 256 + 256, 256, 0, stream>>>(
      WvTb, Wivb, nullptr, nullptr, Ttb, 512, 1024, 1024,
      Wo, b1, bo, bc, 256,
      Wo, Wob, 0, 256,
      nullptr, nullptr, 0);

  // K3: Wc = Wo @ T (pure GEMM, 128 blocks)
  gemm_cv<64, 64, 64, 2, 2, 1, 0><<<128, 256, 0, stream>>>(
      Wob, Ttb, nullptr, nullptr, Wcb, 1024, 512, 1024,
      nullptr, nullptr, nullptr, nullptr, 0,
      nullptr, nullptr, 0, 0,
      nullptr, nullptr, 0);

  // K4f: out (16384x1024 f32) = vit @ Wc^T + bc (A fp32 reg-staged cvt,
  // BK=64 swizzled, depth-2 counted vmcnt, XCD swizzle) — no Xb round-trip.
  gemm_k4f<<<1024, 256, 0, stream>>>(vit, Wcb, bc, (float*)d_out);
}

// Round 19
// 55.815 us; speedup vs baseline: 1.3387x; 1.3387x over previous
//
#include <hip/hip_runtime.h>
#include <stdint.h>
#include <stddef.h>

#define E_DIM 1024

typedef __bf16 v8bf __attribute__((ext_vector_type(8)));
typedef float v4f __attribute__((ext_vector_type(4)));

__device__ __forceinline__ unsigned short f2bf(float x) {
  unsigned int u = __builtin_bit_cast(unsigned int, x);
  u += 0x7fffu + ((u >> 16) & 1u);
  return (unsigned short)(u >> 16);
}

// XOR swizzle for LDS rows >= 128B (involution; both-sides-or-neither).
template <int RB>
__device__ __forceinline__ int swz(int r, int c) {
  if constexpr (RB >= 128) return c ^ ((r & 7) << 4);
  else return c;
}

// constexpr-dispatched s_waitcnt vmcnt(N)
template <int N>
__device__ __forceinline__ void waitcnt_vm() {
  static_assert(N == 0 || N == 4 || N == 8 || N == 12, "add literal");
  if constexpr (N == 0)  asm volatile("s_waitcnt vmcnt(0)" ::: "memory");
  if constexpr (N == 4)  asm volatile("s_waitcnt vmcnt(4)" ::: "memory");
  if constexpr (N == 8)  asm volatile("s_waitcnt vmcnt(8)" ::: "memory");
  if constexpr (N == 12) asm volatile("s_waitcnt vmcnt(12)" ::: "memory");
}

// bf16 global tile (ROWS x BK) -> LDS via global_load_lds, source pre-swizzled.
template <int ROWS, int BK>
__device__ __forceinline__ void stageg(const unsigned short* __restrict__ G, int g0,
                                       int ldg, int k0, char* L, int wid, int lane) {
  constexpr int RB = BK * 2;
  constexpr int ITERS = (ROWS * RB) / 4096;
#pragma unroll
  for (int it = 0; it < ITERS; ++it) {
    int lbase = it * 4096 + wid * 1024;   // wave-uniform LDS byte base
    int lin = lbase + lane * 16;
    int r = lin / RB, cb = lin % RB;
    int gcb = swz<RB>(r, cb);
    const char* g = (const char*)G + ((size_t)(g0 + r) * ldg + k0) * 2 + gcb;
    __builtin_amdgcn_global_load_lds((const __attribute__((address_space(1))) void*)g,
                                     (__attribute__((address_space(3))) void*)(L + lbase),
                                     16, 0, 0);
  }
}

template <int RB>
__device__ __forceinline__ v8bf frag_bf16(const char* L, int r, int kelem) {
  int o = swz<RB>(r, kelem * 2);
  return *(const v8bf*)(L + r * RB + o);
}

// one K-tile of MFMA work from bf16 LDS buffers
template <int BM, int BN, int BK, int FM, int FN>
__device__ __forceinline__ void compute_tile(const char* Al, const char* Bl,
                                             v4f (&acc)[FM][FN],
                                             int wr, int wc, int lr, int kg) {
  constexpr int RBA = BK * 2, RBB = BK * 2;
  constexpr int TMW = BM / 2, TNW = BN / 2;
#pragma unroll
  for (int kk = 0; kk < BK / 32; ++kk) {
    const int ke = kk * 32 + kg * 8;
    v8bf a[FM], b[FN];
#pragma unroll
    for (int mi = 0; mi < FM; ++mi)
      a[mi] = frag_bf16<RBA>(Al, wr * TMW + mi * 16 + lr, ke);
#pragma unroll
    for (int ni = 0; ni < FN; ++ni)
      b[ni] = frag_bf16<RBB>(Bl, wc * TNW + ni * 16 + lr, ke);
#pragma unroll
    for (int mi = 0; mi < FM; ++mi)
#pragma unroll
      for (int ni = 0; ni < FN; ++ni)
        acc[mi][ni] = __builtin_amdgcn_mfma_f32_16x16x32_bf16(a[mi], b[ni], acc[mi][ni], 0, 0, 0);
  }
}

// cvt 4096 fp32 -> bf16 per block; i0 = (base + blkrel) * 1024 + tid
__device__ __forceinline__ void cvt4(const float4* __restrict__ src,
                                     ushort4* __restrict__ dst, int i0) {
#pragma unroll
  for (int j = 0; j < 4; ++j) {
    int i = i0 + j * 256;
    float4 f = src[i];
    ushort4 u;
    u.x = f2bf(f.x); u.y = f2bf(f.y); u.z = f2bf(f.z); u.w = f2bf(f.w);
    dst[i] = u;
  }
}

// matvec: 4 rows/block, y = W@x + b over 1024 cols (W fp32)
__device__ __forceinline__ void mv4(const float* __restrict__ W, const float* __restrict__ x,
                                    const float* __restrict__ b, float* __restrict__ y,
                                    int blkrel, int tid) {
  int r = blkrel * 4 + (tid >> 6);
  int lane = tid & 63;
  float s = 0.f;
  for (int c = lane; c < 1024; c += 64) s += W[(size_t)r * 1024 + c] * x[c];
#pragma unroll
  for (int off = 32; off; off >>= 1) s += __shfl_down(s, off);
  if (lane == 0) y[r] = s + b[r];
}

// ---- prep1 (weights only): transpose+cvt Wv [0,512) || matvec b1 [512,768)
//                            || cvt Wiv [768,1024)
__global__ __launch_bounds__(256) void prep1(const float* __restrict__ Wv,
                                             unsigned short* __restrict__ WvT,
                                             const float* __restrict__ Wiv,
                                             const float* __restrict__ bv,
                                             const float* __restrict__ biv,
                                             float* __restrict__ b1,
                                             unsigned short* __restrict__ Wivb) {
  int bid = blockIdx.x;
  int tid = threadIdx.x;
  if (bid < 512) {
    __shared__ float tile[32][33];
    const int R = 1024, C = 512;
    int nbx = C >> 5;
    int bx = bid % nbx, by = bid / nbx;
    int tx = tid & 31, ty = tid >> 5;
#pragma unroll
    for (int i = 0; i < 32; i += 8)
      tile[ty + i][tx] = Wv[(size_t)(by * 32 + ty + i) * C + bx * 32 + tx];
    __syncthreads();
#pragma unroll
    for (int i = 0; i < 32; i += 8)
      WvT[(size_t)(bx * 32 + ty + i) * R + by * 32 + tx] = f2bf(tile[tx][ty + i]);
  } else if (bid < 768) {
    mv4(Wiv, bv, biv, b1, bid - 512, tid);
  } else {
    cvt4((const float4*)Wiv, (ushort4*)Wivb, (bid - 768) * 1024 + tid);
  }
}

// ---- generic bt-GEMM (K2/K3), depth-4 buffers / 3-in-flight, 1 barrier/phase.
// NT = K/BK multiple of 4 >= 8.
// Tail blocks (>= ngemm): [0,nmv) matvec; [nmv,nmv+ncv1) cvt1; rest cvt2.
template <int BM, int BN, int BK, int FM, int FN, int OUTBF, int XCDSWZ>
__global__ __launch_bounds__(256) void gemm_cv(const unsigned short* __restrict__ A,
                                               const unsigned short* __restrict__ B,
                                               const float* __restrict__ bias,
                                               float* __restrict__ Cf,
                                               unsigned short* __restrict__ Cb,
                                               int M, int N, int K,
                                               const float* __restrict__ mvW,
                                               const float* __restrict__ mvx,
                                               const float* __restrict__ mvb,
                                               float* __restrict__ mvy, int nmv,
                                               const float* __restrict__ csrc1,
                                               unsigned short* __restrict__ cdst1,
                                               int cbase1, int ncv1,
                                               const float* __restrict__ csrc2,
                                               unsigned short* __restrict__ cdst2,
                                               int cbase2) {
  static_assert((BM + BN) * BK * 2 / 1024 / 4 == 4, "vmcnt literals assume 4 loads/tile/wave");
  __shared__ __align__(16) char Al0[BM * BK * 2];
  __shared__ __align__(16) char Al1[BM * BK * 2];
  __shared__ __align__(16) char Al2[BM * BK * 2];
  __shared__ __align__(16) char Al3[BM * BK * 2];
  __shared__ __align__(16) char Bl0[BN * BK * 2];
  __shared__ __align__(16) char Bl1[BN * BK * 2];
  __shared__ __align__(16) char Bl2[BN * BK * 2];
  __shared__ __align__(16) char Bl3[BN * BK * 2];
  const int nbn = N / BN;
  const int ngemm = nbn * (M / BM);
  int bid = blockIdx.x;
  const int tid = threadIdx.x;

  if (bid >= ngemm) {  // tail work
    int rel = bid - ngemm;
    if (rel < nmv) {
      mv4(mvW, mvx, mvb, mvy, rel, tid);
    } else if (rel < nmv + ncv1) {
      cvt4((const float4*)csrc1, (ushort4*)cdst1, (cbase1 + rel - nmv) * 1024 + tid);
    } else {
      cvt4((const float4*)csrc2, (ushort4*)cdst2, (cbase2 + rel - nmv - ncv1) * 1024 + tid);
    }
    return;
  }

  int bm_i, bn_i;
  if (XCDSWZ) {
    int x = bid & 7, j = bid >> 3;
    bm_i = x + ((j >> 3) << 3);
    bn_i = j & 7;
  } else {
    bm_i = bid / nbn;
    bn_i = bid % nbn;
  }
  const int bm0 = bm_i * BM, bn0 = bn_i * BN;

  constexpr int TMW = BM / 2, TNW = BN / 2;
  const int lane = tid & 63;
  const int wid = tid >> 6;
  const int wr = wid >> 1, wc = wid & 1;
  const int lr = lane & 15;
  const int kg = lane >> 4;

  v4f acc[FM][FN];
#pragma unroll
  for (int i = 0; i < FM; ++i)
#pragma unroll
    for (int j = 0; j < FN; ++j) acc[i][j] = 0.f;

  const int NT = K / BK;  // multiple of 4, >= 8

  stageg<BM, BK>(A, bm0, K, 0 * BK, Al0, wid, lane);
  stageg<BN, BK>(B, bn0, K, 0 * BK, Bl0, wid, lane);
  stageg<BM, BK>(A, bm0, K, 1 * BK, Al1, wid, lane);
  stageg<BN, BK>(B, bn0, K, 1 * BK, Bl1, wid, lane);
  stageg<BM, BK>(A, bm0, K, 2 * BK, Al2, wid, lane);
  stageg<BN, BK>(B, bn0, K, 2 * BK, Bl2, wid, lane);

#define GEMM_PHASE(CA, CB, SA, SB, TNXT, W)                              \
  waitcnt_vm<W>();                                                       \
  __builtin_amdgcn_s_barrier();                                          \
  __builtin_amdgcn_sched_barrier(0);                                     \
  if ((TNXT) < NT) {                                                     \
    stageg<BM, BK>(A, bm0, K, (TNXT)*BK, SA, wid, lane);                 \
    stageg<BN, BK>(B, bn0, K, (TNXT)*BK, SB, wid, lane);                 \
  }                                                                      \
  __builtin_amdgcn_s_setprio(1);                                         \
  compute_tile<BM, BN, BK, FM, FN>(CA, CB, acc, wr, wc, lr, kg);         \
  __builtin_amdgcn_s_setprio(0);                                         \
  __builtin_amdgcn_sched_barrier(0);

  for (int t = 0; t + 8 <= NT; t += 4) {
    GEMM_PHASE(Al0, Bl0, Al3, Bl3, t + 3, 8)
    GEMM_PHASE(Al1, Bl1, Al0, Bl0, t + 4, 8)
    GEMM_PHASE(Al2, Bl2, Al1, Bl1, t + 5, 8)
    GEMM_PHASE(Al3, Bl3, Al2, Bl2, t + 6, 8)
  }
  GEMM_PHASE(Al0, Bl0, Al3, Bl3, NT - 1, 8)
  GEMM_PHASE(Al1, Bl1, Al0, Bl0, NT, 8)
  GEMM_PHASE(Al2, Bl2, Al1, Bl1, NT, 4)
  GEMM_PHASE(Al3, Bl3, Al2, Bl2, NT, 0)
#undef GEMM_PHASE

#pragma unroll
  for (int ni = 0; ni < FN; ++ni) {
    int col = bn0 + wc * TNW + ni * 16 + lr;
    float bz = bias ? bias[col] : 0.f;
#pragma unroll
    for (int mi = 0; mi < FM; ++mi) {
      int row0 = bm0 + wr * TMW + mi * 16 + kg * 4;
#pragma unroll
      for (int r = 0; r < 4; ++r) {
        float v = acc[mi][ni][r] + bz;
        if (OUTBF) Cb[(size_t)(row0 + r) * N + col] = f2bf(v);
        else       Cf[(size_t)(row0 + r) * N + col] = v;
      }
    }
  }
}

// ---- K4: 128x128 tile, BK=64 (RB=128 -> XOR swizzle active, conflict-free
// ds_read_b128), depth-2, NT=8 static. Phase t: vmcnt(8) [tile t+1 in flight];
// barrier; setprio+32 MFMA; barrier; stage tile t+2 into just-freed buffer.
__global__ __launch_bounds__(256) void gemm_k4(const unsigned short* __restrict__ A,
                                               const unsigned short* __restrict__ B,
                                               const float* __restrict__ bias,
                                               float* __restrict__ C,
                                               int M, int N, int K) {
  __shared__ __align__(16) char Al0[128 * 128];
  __shared__ __align__(16) char Al1[128 * 128];
  __shared__ __align__(16) char Bl0[128 * 128];
  __shared__ __align__(16) char Bl1[128 * 128];
  const int tid = threadIdx.x;
  const int lane = tid & 63, wid = tid >> 6;
  const int wr = wid >> 1, wc = wid & 1;
  const int lr = lane & 15, kg = lane >> 4;

  int bid = blockIdx.x;           // 1024 blocks, nbn = 8
  int x = bid & 7, j = bid >> 3;  // XCD row-band swizzle (proven)
  const int bm0 = (x + ((j >> 3) << 3)) * 128;
  const int bn0 = (j & 7) * 128;

  v4f acc[4][4];
#pragma unroll
  for (int i = 0; i < 4; ++i)
#pragma unroll
    for (int jj = 0; jj < 4; ++jj) acc[i][jj] = 0.f;

  // prologue: tiles 0,1 (8 loads each per wave)
  stageg<128, 64>(A, bm0, K, 0, Al0, wid, lane);
  stageg<128, 64>(B, bn0, K, 0, Bl0, wid, lane);
  stageg<128, 64>(A, bm0, K, 64, Al1, wid, lane);
  stageg<128, 64>(B, bn0, K, 64, Bl1, wid, lane);

#define K4P(CA, CB, TN2, W)                                              \
  waitcnt_vm<W>();                                                       \
  __builtin_amdgcn_s_barrier();                                          \
  __builtin_amdgcn_sched_barrier(0);                                     \
  __builtin_amdgcn_s_setprio(1);                                         \
  compute_tile<128, 128, 64, 4, 4>(CA, CB, acc, wr, wc, lr, kg);         \
  __builtin_amdgcn_s_setprio(0);                                         \
  __builtin_amdgcn_sched_barrier(0);                                     \
  __builtin_amdgcn_s_barrier();                                          \
  if constexpr ((TN2) < 8) {                                             \
    stageg<128, 64>(A, bm0, K, (TN2)*64, CA, wid, lane);                 \
    stageg<128, 64>(B, bn0, K, (TN2)*64, CB, wid, lane);                 \
  }

  K4P(Al0, Bl0, 2, 8)   // t=0
  K4P(Al1, Bl1, 3, 8)   // t=1
  K4P(Al0, Bl0, 4, 8)   // t=2
  K4P(Al1, Bl1, 5, 8)   // t=3
  K4P(Al0, Bl0, 6, 8)   // t=4
  K4P(Al1, Bl1, 7, 8)   // t=5
  K4P(Al0, Bl0, 8, 8)   // t=6 (tile 7 in flight)
  K4P(Al1, Bl1, 8, 0)   // t=7 (drain)
#undef K4P

#pragma unroll
  for (int ni = 0; ni < 4; ++ni) {
    int col = bn0 + wc * 64 + ni * 16 + lr;
    float bz = bias[col];
#pragma unroll
    for (int mi = 0; mi < 4; ++mi) {
      int row0 = bm0 + wr * 64 + mi * 16 + kg * 4;
#pragma unroll
      for (int r = 0; r < 4; ++r)
        C[(size_t)(row0 + r) * N + col] = acc[mi][ni][r] + bz;
    }
  }
}

extern "C" void kernel_launch(void* const* d_in, const int* in_sizes, int n_in,
                              void* d_out, int out_size, void* d_ws, size_t ws_size,
                              hipStream_t stream) {
  // softmax over singleton axis == 1  =>  out = x @ (Wo·Wiv·Wv)^T + [Wo·(Wiv·bv+biv)+bo]
  const float* vit = (const float*)d_in[1];
  const float* Wv  = (const float*)d_in[6];
  const float* bv  = (const float*)d_in[7];
  const float* ipw = (const float*)d_in[8];
  const float* ipb = (const float*)d_in[9];
  const float* Wo  = (const float*)d_in[10];
  const float* bo  = (const float*)d_in[11];
  const float* Wiv = ipw + 2 * E_DIM * E_DIM;
  const float* biv = ipb + 2 * E_DIM;

  char* ws = (char*)d_ws;
  unsigned short* Xb   = (unsigned short*)(ws);               // 16384x512 bf16, 16 MB
  unsigned short* Wivb = (unsigned short*)(ws + (16 << 20));  // 1024x1024 bf16, 2 MB
  unsigned short* Wob  = (unsigned short*)(ws + (18 << 20));  // 1024x1024 bf16, 2 MB
  unsigned short* WvTb = (unsigned short*)(ws + (20 << 20));  // 512x1024 bf16, 1 MB
  unsigned short* Ttb  = (unsigned short*)(ws + (21 << 20));  // 512x1024 bf16 (T^T)
  unsigned short* Wcb  = (unsigned short*)(ws + (22 << 20));  // 1024x512 bf16
  float* b1 = (float*)(ws + (23 << 20));
  float* bc = (float*)(ws + (23 << 20) + 4096);

  // K1 (weights only): transpose Wv -> WvT || matvec b1 || cvt Wiv
  prep1<<<1024, 256, 0, stream>>>(Wv, WvTb, Wiv, bv, biv, b1, Wivb);

  // K2: T^T = WvT @ Wiv^T (128) || bc matvec (256) || cvt Wo (256) || cvt vit half1 (1024)
  gemm_cv<64, 64, 64, 2, 2, 1, 0><<<128 + 256 + 256 + 1024, 256, 0, stream>>>(
      WvTb, Wivb, nullptr, nullptr, Ttb, 512, 1024, 1024,
      Wo, b1, bo, bc, 256,
      Wo, Wob, 0, 256,
      vit, Xb, 0);

  // K3: Wc = Wo @ T (128) || cvt vit half2 (1024)
  gemm_cv<64, 64, 64, 2, 2, 1, 0><<<128 + 1024, 256, 0, stream>>>(
      Wob, Ttb, nullptr, nullptr, Wcb, 1024, 512, 1024,
      nullptr, nullptr, nullptr, nullptr, 0,
      vit, Xb, 1024, 1024,
      vit, Xb, 0);

  // K4: out (16384x1024 f32) = Xb @ Wc^T + bc (BK=64 swizzled, depth-2, XCD swizzle)
  gemm_k4<<<1024, 256, 0, stream>>>(Xb, Wcb, bc, (float*)d_out, 16384, 1024, 512);
}